// Round 9
// baseline (472.144 us; speedup 1.0000x reference)
//
#include <hip/hip_runtime.h>
#include <hip/hip_bf16.h>

typedef __hip_bfloat16 bf16;
typedef unsigned short u16;
typedef __attribute__((ext_vector_type(8))) short s8;   // 8 bf16 = one MFMA A/B fragment
typedef __attribute__((ext_vector_type(4))) float f4;   // MFMA C/D fragment

#define NRUNS 3
#define NTREE 128
#define TT    255
#define DD    256
#define VPAD  10016    /* vocab padded to 32 */
#define PAD   258      /* LDS row stride in u16 for 256-wide rows */

__device__ __forceinline__ float bits2f(u16 b){ union{unsigned u; float f;} x; x.u = ((unsigned)b)<<16; return x.f; }
__device__ __forceinline__ u16   f2bits(float f){ bf16 h = __float2bfloat16(f); return *(u16*)&h; }
__device__ __forceinline__ float sigm(float x){ return 1.f/(1.f+__expf(-x)); }
__device__ __forceinline__ float tanh_(float x){ return 1.f - 2.f/(__expf(2.f*x)+1.f); }

// ---------------- dtype autodetect (proven) ----------------
__global__ void k_detect(const u16* __restrict__ raw, int* __restrict__ flag){
    int t = threadIdx.x;
    int hit = 0;
    if (t < 128){
        u16 w = raw[2*t];
        int e = (w >> 7) & 0xFF;
        hit = (e >= 100 && e <= 141) ? 1 : 0;
    }
    __shared__ int cnt;
    if (t == 0) cnt = 0;
    __syncthreads();
    atomicAdd(&cnt, hit);
    __syncthreads();
    if (t == 0) flag[0] = (cnt >= 64) ? 1 : 0;
}

__device__ __forceinline__ u16 cvt1b(const void* p, int i, int isb){
    return isb ? ((const u16*)p)[i] : f2bits(((const float*)p)[i]);
}
__device__ __forceinline__ float cvt1f(const void* p, int i, int isb){
    return isb ? bits2f(((const u16*)p)[i]) : ((const float*)p)[i];
}

// fused any->bf16 (emb + 4 weights) AND any->f32 (biases + FC) conversion, one dispatch
#define L_EMB  (10000*256)
#define L_EMBP (VPAD*256)
#define L_WIOU (768*256)
#define L_UIOU (768*256)
#define L_WF   (256*256)
#define L_UF   (256*256)
#define L_ALL  (L_EMBP + L_WIOU + L_UIOU + L_WF + L_UF)
#define S_BIOU 768
#define S_BF   256
#define S_F1W  (128*256)
#define S_F1B  128
#define S_F2W  (3*128)
#define S_F2B  3
#define S_ALL  (S_BIOU+S_BF+S_F1W+S_F1B+S_F2W+S_F2B)
__global__ void k_cvtall(const void* __restrict__ s0, const void* __restrict__ s1,
                         const void* __restrict__ s2, const void* __restrict__ s3,
                         const void* __restrict__ s4,
                         const void* __restrict__ t0, const void* __restrict__ t1,
                         const void* __restrict__ t2, const void* __restrict__ t3,
                         const void* __restrict__ t4, const void* __restrict__ t5,
                         u16* __restrict__ d0, u16* __restrict__ d1, u16* __restrict__ d2,
                         u16* __restrict__ d3, u16* __restrict__ d4,
                         float* __restrict__ e0, float* __restrict__ e1, float* __restrict__ e2,
                         float* __restrict__ e3, float* __restrict__ e4, float* __restrict__ e5,
                         const int* __restrict__ flag){
    int isb = flag[0];
    for (int i = blockIdx.x*blockDim.x + threadIdx.x; i < L_ALL + S_ALL; i += gridDim.x*blockDim.x){
        int j = i;
        if (j < L_EMBP){ d0[j] = (j < L_EMB) ? cvt1b(s0, j, isb) : (u16)0; continue; } j -= L_EMBP;
        if (j < L_WIOU){ d1[j] = cvt1b(s1, j, isb); continue; } j -= L_WIOU;
        if (j < L_UIOU){ d2[j] = cvt1b(s2, j, isb); continue; } j -= L_UIOU;
        if (j < L_WF){ d3[j] = cvt1b(s3, j, isb); continue; } j -= L_WF;
        if (j < L_UF){ d4[j] = cvt1b(s4, j, isb); continue; } j -= L_UF;
        if (j < S_BIOU){ e0[j] = cvt1f(t0, j, isb); continue; } j -= S_BIOU;
        if (j < S_BF){ e1[j] = cvt1f(t1, j, isb); continue; } j -= S_BF;
        if (j < S_F1W){ e2[j] = cvt1f(t2, j, isb); continue; } j -= S_F1W;
        if (j < S_F1B){ e3[j] = cvt1f(t3, j, isb); continue; } j -= S_F1B;
        if (j < S_F2W){ e4[j] = cvt1f(t4, j, isb); continue; } j -= S_F2W;
        e5[j] = cvt1f(t5, j, isb);
    }
}

__device__ __forceinline__ s8 ldB16(const u16* p){
    union { uint4 q; s8 v; } u;
    u.q = *(const uint4*)p;
    return u.v;
}
__device__ __forceinline__ s8 ldsA(const u16* p){
    union { unsigned w[4]; s8 v; } u;
    u.w[0] = *(const unsigned*)(p);
    u.w[1] = *(const unsigned*)(p+2);
    u.w[2] = *(const unsigned*)(p+4);
    u.w[3] = *(const unsigned*)(p+6);
    return u.v;
}
#define MFMA(acc,a,b) acc = __builtin_amdgcn_mfma_f32_16x16x32_bf16(a, b, acc, 0, 0, 0)

// ---------------- vocab-space precompute (round-8 proven) ----------------
__global__ __launch_bounds__(512, 4)
void k_vocab2(const u16* __restrict__ embb,
              const u16* __restrict__ Wiou, const u16* __restrict__ Wfm,
              const u16* __restrict__ Ufm,  const float* __restrict__ biou_f,
              u16* __restrict__ E_iou, u16* __restrict__ E_f,
              u16* __restrict__ H0, u16* __restrict__ C0, u16* __restrict__ HU0)
{
    __shared__ u16 hs[32*PAD];
    const int t = threadIdx.x, w = t>>6, lane = t&63, ln = lane&15, q = lane>>4;
    const int r0 = blockIdx.x*32, d0 = w*32;

    const u16* Bp[8];
    #pragma unroll
    for (int g = 0; g < 4; g++)
      #pragma unroll
      for (int nc = 0; nc < 2; nc++){
        int nn = d0 + nc*16 + ln;
        Bp[g*2+nc] = (g < 3) ? (Wiou + (size_t)(g*256+nn)*DD) : (Wfm + (size_t)nn*DD);
      }
    const u16* a0p = embb + (size_t)(r0+ln)*DD;
    const u16* a1p = embb + (size_t)(r0+16+ln)*DD;
    f4 acc[8][2];
    #pragma unroll
    for (int nt = 0; nt < 8; nt++){ acc[nt][0] = (f4){0,0,0,0}; acc[nt][1] = (f4){0,0,0,0}; }
    #pragma unroll 2
    for (int ks = 0; ks < 8; ks++){
        int ko = ks*32 + q*8;
        s8 a0 = ldB16(a0p + ko);
        s8 a1 = ldB16(a1p + ko);
        #pragma unroll
        for (int nt = 0; nt < 8; nt++){
            s8 bb = ldB16(Bp[nt] + ko);
            MFMA(acc[nt][0], a0, bb);
            MFMA(acc[nt][1], a1, bb);
        }
    }
    #pragma unroll
    for (int nc = 0; nc < 2; nc++){
        int d = d0 + nc*16 + ln;
        float bi = biou_f[d], bo = biou_f[256+d], bu = biou_f[512+d];
        #pragma unroll
        for (int ms = 0; ms < 2; ms++)
          #pragma unroll
          for (int r = 0; r < 4; r++){
            int vrow = r0 + ms*16 + q*4 + r;
            float ei = acc[0*2+nc][ms][r];
            float eo = acc[1*2+nc][ms][r];
            float eu = acc[2*2+nc][ms][r];
            float ef = acc[3*2+nc][ms][r];
            size_t eb = (size_t)vrow*768 + d;
            E_iou[eb]       = f2bits(ei);
            E_iou[eb + 256] = f2bits(eo);
            E_iou[eb + 512] = f2bits(eu);
            E_f[(size_t)vrow*DD + d] = f2bits(ef);
            float cc = sigm(ei + bi)*tanh_(eu + bu);
            float hh = sigm(eo + bo)*tanh_(cc);
            C0[(size_t)vrow*DD + d] = f2bits(cc);
            H0[(size_t)vrow*DD + d] = f2bits(hh);
            hs[(ms*16 + q*4 + r)*PAD + d] = f2bits(hh);
        }
    }
    __syncthreads();

    f4 hacc[2][2];
    #pragma unroll
    for (int nt = 0; nt < 2; nt++){ hacc[nt][0] = (f4){0,0,0,0}; hacc[nt][1] = (f4){0,0,0,0}; }
    const u16* Bf0 = Ufm + (size_t)(d0 + ln)*DD;
    const u16* Bf1 = Ufm + (size_t)(d0 + 16 + ln)*DD;
    #pragma unroll 2
    for (int ks = 0; ks < 8; ks++){
        int ko = ks*32 + q*8;
        s8 a0 = ldsA(&hs[ln*PAD + ko]);
        s8 a1 = ldsA(&hs[(16+ln)*PAD + ko]);
        s8 b0 = ldB16(Bf0 + ko);
        s8 b1 = ldB16(Bf1 + ko);
        MFMA(hacc[0][0], a0, b0); MFMA(hacc[0][1], a1, b0);
        MFMA(hacc[1][0], a0, b1); MFMA(hacc[1][1], a1, b1);
    }
    #pragma unroll
    for (int nc = 0; nc < 2; nc++){
        int d = d0 + nc*16 + ln;
        #pragma unroll
        for (int ms = 0; ms < 2; ms++)
          #pragma unroll
          for (int r = 0; r < 4; r++){
            int vrow = r0 + ms*16 + q*4 + r;
            HU0[(size_t)vrow*DD + d] = f2bits(hacc[nc][ms][r]);
        }
    }
}

// ---------------- k_lvl1: level 1 with k_edge0 fused via MFMA linearity ----------------
// GEMM-U: acc = H0[v1]@Uiou^T + H0[v2]@Uiou^T  (== hsum@U, exact — no bf16 hsum rounding)
// cs     = sig(E_f[own]+bf+HU0[v1])*C0[v1] + sig(...v2)*C0[v2]   (epilogue table gathers)
// rest identical to k_lvl (round-7 proven shape). cnt=64, S=128, row>>13 = run.
__global__ __launch_bounds__(512, 4)
void k_lvl1(const int* __restrict__ f0, const int* __restrict__ f1, const int* __restrict__ f2,
            const u16* __restrict__ E_iou, const u16* __restrict__ E_f,
            const u16* __restrict__ H0, const u16* __restrict__ C0, const u16* __restrict__ HU0,
            const u16* __restrict__ Uiou, const u16* __restrict__ Ufm,
            const float* __restrict__ biou_f, const float* __restrict__ bf_f,
            u16* __restrict__ hsum_out, u16* __restrict__ fcsum_out)
{
    __shared__ u16 hs[32*PAD];
    const int t = threadIdx.x, w = t>>6, lane = t&63, ln = lane&15, q = lane>>4;
    const int r0 = blockIdx.x*32, d0 = w*32;

    // per-lane A-row child feats (A rows indexed by ln)
    const u16 *pa1[2], *pa2[2];
    #pragma unroll
    for (int ms = 0; ms < 2; ms++){
        int row = r0 + ms*16 + ln;
        int run = row >> 13, rem = row & 8191;
        int b = rem >> 6, jj = rem & 63;
        const int* fp = (run==0) ? f0 : ((run==1) ? f1 : f2);
        pa1[ms] = H0 + (size_t)fp[b*TT + 2*jj]*DD;
        pa2[ms] = H0 + (size_t)fp[b*TT + 2*jj + 1]*DD;
    }
    // epilogue-row feats: own + children + lvl-2 parent
    int fo[2][4], v1e[2][4], v2e[2][4], featp[2][2];
    #pragma unroll
    for (int ms = 0; ms < 2; ms++)
      #pragma unroll
      for (int r = 0; r < 4; r++){
        int rho = r0 + ms*16 + q*4 + r;
        int run = rho >> 13, rem = rho & 8191;
        int b = rem >> 6, jj = rem & 63;
        const int* fp = (run==0) ? f0 : ((run==1) ? f1 : f2);
        fo[ms][r]  = fp[b*TT + 128 + jj];
        v1e[ms][r] = fp[b*TT + 2*jj];
        v2e[ms][r] = fp[b*TT + 2*jj + 1];
        if ((r&1)==0) featp[ms][r>>1] = fp[b*TT + 192 + (jj>>1)];
      }

    // ---- GEMM-U: two H0 A-streams, shared B ----
    f4 acc[6][2];
    #pragma unroll
    for (int nt = 0; nt < 6; nt++){ acc[nt][0] = (f4){0,0,0,0}; acc[nt][1] = (f4){0,0,0,0}; }
    {
        const u16* Bp[6];
        #pragma unroll
        for (int nt = 0; nt < 6; nt++){
            int n = (nt>>1)*256 + d0 + (nt&1)*16 + ln;
            Bp[nt] = Uiou + (size_t)n*DD;
        }
        #pragma unroll 2
        for (int ks = 0; ks < 8; ks++){
            int ko = ks*32 + q*8;
            s8 a10 = ldB16(pa1[0] + ko);
            s8 a11 = ldB16(pa1[1] + ko);
            s8 a20 = ldB16(pa2[0] + ko);
            s8 a21 = ldB16(pa2[1] + ko);
            #pragma unroll
            for (int nt = 0; nt < 6; nt++){
                s8 bb = ldB16(Bp[nt] + ko);
                MFMA(acc[nt][0], a10, bb);
                MFMA(acc[nt][0], a20, bb);
                MFMA(acc[nt][1], a11, bb);
                MFMA(acc[nt][1], a21, bb);
            }
        }
    }

    // ---- epilogue: fused edge0 fcsum + cell update; hsum pair-reduce in registers ----
    float cv[2][2][4];
    #pragma unroll
    for (int nc = 0; nc < 2; nc++){
        int d = d0 + nc*16 + ln;
        float bi = biou_f[d], bo = biou_f[256+d], bu = biou_f[512+d];
        float bfv = bf_f[d];
        #pragma unroll
        for (int ms = 0; ms < 2; ms++){
            float hv[4];
            #pragma unroll
            for (int r = 0; r < 4; r++){
                size_t eb = (size_t)fo[ms][r]*768 + d;
                float iv = acc[0+nc][ms][r] + bits2f(E_iou[eb])       + bi;
                float ov = acc[2+nc][ms][r] + bits2f(E_iou[eb + 256]) + bo;
                float uv = acc[4+nc][ms][r] + bits2f(E_iou[eb + 512]) + bu;
                float e  = bits2f(E_f[(size_t)fo[ms][r]*DD + d]) + bfv;
                size_t b1 = (size_t)v1e[ms][r]*DD + d;
                size_t b2 = (size_t)v2e[ms][r]*DD + d;
                float fa = sigm(e + bits2f(HU0[b1]));
                float fb = sigm(e + bits2f(HU0[b2]));
                float cs = fa*bits2f(C0[b1]) + fb*bits2f(C0[b2]);
                float c = sigm(iv)*tanh_(uv) + cs;
                float h = sigm(ov)*tanh_(c);
                cv[nc][ms][r] = c;
                hv[r] = h;
                hs[(ms*16 + q*4 + r)*PAD + d] = f2bits(h);
            }
            int prow = (r0>>1) + ms*8 + q*2;
            hsum_out[(size_t)prow*DD + d]     = f2bits(hv[0] + hv[1]);
            hsum_out[(size_t)(prow+1)*DD + d] = f2bits(hv[2] + hv[3]);
        }
    }

    // ---- GEMM-C: hU = h@Uf^T, fc for lvl-2, pair-reduce (round-7 proven) ----
    __syncthreads();
    f4 hacc[2][2];
    #pragma unroll
    for (int nt = 0; nt < 2; nt++){ hacc[nt][0] = (f4){0,0,0,0}; hacc[nt][1] = (f4){0,0,0,0}; }
    const u16* Bf0 = Ufm + (size_t)(d0 + ln)*DD;
    const u16* Bf1 = Ufm + (size_t)(d0 + 16 + ln)*DD;
    #pragma unroll 2
    for (int ks = 0; ks < 8; ks++){
        int ko = ks*32 + q*8;
        s8 a0 = ldsA(&hs[ln*PAD + ko]);
        s8 a1 = ldsA(&hs[(16+ln)*PAD + ko]);
        s8 b0 = ldB16(Bf0 + ko);
        s8 b1 = ldB16(Bf1 + ko);
        MFMA(hacc[0][0], a0, b0); MFMA(hacc[0][1], a1, b0);
        MFMA(hacc[1][0], a0, b1); MFMA(hacc[1][1], a1, b1);
    }
    #pragma unroll
    for (int nc = 0; nc < 2; nc++){
        int d = d0 + nc*16 + ln;
        float bfv = bf_f[d];
        #pragma unroll
        for (int ms = 0; ms < 2; ms++){
            float fs0, fs1;
            #pragma unroll
            for (int r = 0; r < 4; r++){
                float ef = bits2f(E_f[(size_t)featp[ms][r>>1]*DD + d]);
                float fc = sigm(ef + bfv + hacc[nc][ms][r]) * cv[nc][ms][r];
                if (r == 0) fs0 = fc;
                else if (r == 1) fs0 += fc;
                else if (r == 2) fs1 = fc;
                else fs1 += fc;
            }
            int prow = (r0>>1) + ms*8 + q*2;
            fcsum_out[(size_t)prow*DD + d]     = f2bits(fs0);
            fcsum_out[(size_t)(prow+1)*DD + d] = f2bits(fs1);
        }
    }
}

// ---------------- per-level kernel, lvl>=2 (round-7 proven shape: no E staging) ----------------
__global__ __launch_bounds__(512, 4)
void k_lvl(int lvl, int cLog,
           const int* __restrict__ f0, const int* __restrict__ f1, const int* __restrict__ f2,
           const u16* __restrict__ E_iou, const u16* __restrict__ E_f,
           const u16* __restrict__ Uiou, const u16* __restrict__ Ufm,
           const float* __restrict__ biou_f, const float* __restrict__ bf_f,
           const u16* __restrict__ hsum_in, const u16* __restrict__ fcsum_in,
           u16* __restrict__ hsum_out, u16* __restrict__ fcsum_out,
           u16* __restrict__ hroot)
{
    __shared__ u16 hs[32*PAD];
    const int t = threadIdx.x, w = t>>6, lane = t&63, ln = lane&15, q = lane>>4;
    const int cnt = 1 << cLog, S = 256 - 2*cnt;
    const int r0 = blockIdx.x*32, d0 = w*32;
    const bool haveP = (lvl < 7);

    int feat[2][4], featp[2][2];
    #pragma unroll
    for (int ms = 0; ms < 2; ms++)
      #pragma unroll
      for (int r = 0; r < 4; r++){
        int rho = r0 + ms*16 + q*4 + r;
        int run = rho >> (7+cLog);
        int rem = rho & ((1<<(7+cLog)) - 1);
        int b = rem >> cLog, jj = rem & (cnt-1);
        const int* fp = (run==0) ? f0 : ((run==1) ? f1 : f2);
        feat[ms][r] = fp[b*TT + S + jj];
        if (haveP && (r&1)==0)
            featp[ms][r>>1] = fp[b*TT + (256-cnt) + (jj>>1)];
      }

    f4 acc[6][2];
    #pragma unroll
    for (int nt = 0; nt < 6; nt++){ acc[nt][0] = (f4){0,0,0,0}; acc[nt][1] = (f4){0,0,0,0}; }
    {
        const u16* a0p = hsum_in + (size_t)(r0+ln)*DD;
        const u16* a1p = hsum_in + (size_t)(r0+16+ln)*DD;
        const u16* Bp[6];
        #pragma unroll
        for (int nt = 0; nt < 6; nt++){
            int n = (nt>>1)*256 + d0 + (nt&1)*16 + ln;
            Bp[nt] = Uiou + (size_t)n*DD;
        }
        #pragma unroll 2
        for (int ks = 0; ks < 8; ks++){
            int ko = ks*32 + q*8;
            s8 a0 = ldB16(a0p + ko);
            s8 a1 = ldB16(a1p + ko);
            #pragma unroll
            for (int nt = 0; nt < 6; nt++){
                s8 bb = ldB16(Bp[nt] + ko);
                MFMA(acc[nt][0], a0, bb);
                MFMA(acc[nt][1], a1, bb);
            }
        }
    }

    float cv[2][2][4];
    #pragma unroll
    for (int nc = 0; nc < 2; nc++){
        int d = d0 + nc*16 + ln;
        float bi = biou_f[d], bo = biou_f[256+d], bu = biou_f[512+d];
        #pragma unroll
        for (int ms = 0; ms < 2; ms++){
            float hv[4];
            #pragma unroll
            for (int r = 0; r < 4; r++){
                int rho = r0 + ms*16 + q*4 + r;
                size_t eb = (size_t)feat[ms][r]*768 + d;
                float iv = acc[0+nc][ms][r] + bits2f(E_iou[eb])       + bi;
                float ov = acc[2+nc][ms][r] + bits2f(E_iou[eb + 256]) + bo;
                float uv = acc[4+nc][ms][r] + bits2f(E_iou[eb + 512]) + bu;
                float cs = bits2f(fcsum_in[(size_t)rho*DD + d]);
                float c = sigm(iv)*tanh_(uv) + cs;
                float h = sigm(ov)*tanh_(c);
                cv[nc][ms][r] = c;
                hv[r] = h;
                if (haveP) hs[(ms*16 + q*4 + r)*PAD + d] = f2bits(h);
                else       hroot[(size_t)rho*DD + d] = f2bits(h);
            }
            if (haveP){
                int prow = (r0>>1) + ms*8 + q*2;
                hsum_out[(size_t)prow*DD + d]     = f2bits(hv[0] + hv[1]);
                hsum_out[(size_t)(prow+1)*DD + d] = f2bits(hv[2] + hv[3]);
            }
        }
    }

    if (haveP){
        __syncthreads();
        f4 hacc[2][2];
        #pragma unroll
        for (int nt = 0; nt < 2; nt++){ hacc[nt][0] = (f4){0,0,0,0}; hacc[nt][1] = (f4){0,0,0,0}; }
        const u16* Bf0 = Ufm + (size_t)(d0 + ln)*DD;
        const u16* Bf1 = Ufm + (size_t)(d0 + 16 + ln)*DD;
        #pragma unroll 2
        for (int ks = 0; ks < 8; ks++){
            int ko = ks*32 + q*8;
            s8 a0 = ldsA(&hs[ln*PAD + ko]);
            s8 a1 = ldsA(&hs[(16+ln)*PAD + ko]);
            s8 b0 = ldB16(Bf0 + ko);
            s8 b1 = ldB16(Bf1 + ko);
            MFMA(hacc[0][0], a0, b0); MFMA(hacc[0][1], a1, b0);
            MFMA(hacc[1][0], a0, b1); MFMA(hacc[1][1], a1, b1);
        }
        #pragma unroll
        for (int nc = 0; nc < 2; nc++){
            int d = d0 + nc*16 + ln;
            float bfv = bf_f[d];
            #pragma unroll
            for (int ms = 0; ms < 2; ms++){
                float fs0, fs1;
                #pragma unroll
                for (int r = 0; r < 4; r++){
                    float ef = bits2f(E_f[(size_t)featp[ms][r>>1]*DD + d]);
                    float fc = sigm(ef + bfv + hacc[nc][ms][r]) * cv[nc][ms][r];
                    if (r == 0) fs0 = fc;
                    else if (r == 1) fs0 += fc;
                    else if (r == 2) fs1 = fc;
                    else fs1 += fc;
                }
                int prow = (r0>>1) + ms*8 + q*2;
                fcsum_out[(size_t)prow*DD + d]     = f2bits(fs0);
                fcsum_out[(size_t)(prow+1)*DD + d] = f2bits(fs1);
            }
        }
    }
}

// ---------------- final: bilinear combine + MLP (proven epilogue) ----------------
__global__ __launch_bounds__(256)
void k_final(const u16* __restrict__ hroot,
             const float* __restrict__ fc1w, const float* __restrict__ fc1b,
             const float* __restrict__ fc2w, const float* __restrict__ fc2b,
             void* __restrict__ out, const int* __restrict__ flag)
{
    int b = blockIdx.x, t = threadIdx.x;
    __shared__ float sprod[DD];
    __shared__ float shb[DD];
    __shared__ float shid[128];
    float hc  = bits2f(hroot[(0*NTREE + b)*DD + t]);
    float ha  = bits2f(hroot[(1*NTREE + b)*DD + t]);
    float hbv = bits2f(hroot[(2*NTREE + b)*DD + t]);
    sprod[t] = hc * ha;
    shb[t]   = hbv;
    __syncthreads();
    for (int s = 128; s > 0; s >>= 1){
        if (t < s) sprod[t] += sprod[t + s];
        __syncthreads();
    }
    float dot = sprod[0];
    if (t < 128){
        float acc = fc1b[t];
        for (int k = 0; k < DD; k++)
            acc = fmaf(dot * shb[k], fc1w[t*DD + k], acc);
        shid[t] = fmaxf(acc, 0.f);
    }
    __syncthreads();
    if (t < 3){
        float acc = fc2b[t];
        for (int j = 0; j < 128; j++)
            acc = fmaf(fc2w[t*128 + j], shid[j], acc);
        float v = fmaxf(acc, 0.f);
        if (flag[0]) ((bf16*)out)[b*3 + t] = __float2bfloat16(v);
        else         ((float*)out)[b*3 + t] = v;
    }
}

extern "C" void kernel_launch(void* const* d_in, const int* in_sizes, int n_in,
                              void* d_out, int out_size, void* d_ws, size_t ws_size,
                              hipStream_t stream)
{
    const int* f0 = (const int*)d_in[0];
    const int* f1 = (const int*)d_in[1];
    const int* f2 = (const int*)d_in[2];
    // d_in[3..7] static forest metadata — unused (structure compile-time known)
    const void* emb  = d_in[8];
    const void* Wiou = d_in[9];
    const void* biou = d_in[10];
    const void* Uiou = d_in[11];
    const void* Wf   = d_in[12];
    const void* bfv  = d_in[13];
    const void* Uf   = d_in[14];
    const void* fc1w = d_in[15];
    const void* fc1b = d_in[16];
    const void* fc2w = d_in[17];
    const void* fc2b = d_in[18];

    char* base = (char*)d_ws;
    size_t off = 0;
    auto take = [&](size_t bytes) -> char* {
        char* p = base + off;
        off = (off + bytes + 255) & ~(size_t)255;
        return p;
    };
    int*   flag   = (int*)  take(256);
    u16*   embb   = (u16*)  take((size_t)L_EMBP*2);
    u16*   wioub  = (u16*)  take((size_t)L_WIOU*2);
    u16*   uioub  = (u16*)  take((size_t)L_UIOU*2);
    u16*   wfb    = (u16*)  take((size_t)L_WF*2);
    u16*   ufb    = (u16*)  take((size_t)L_UF*2);
    float* biou_f = (float*)take(S_BIOU*4);
    float* bf_f   = (float*)take(S_BF*4);
    float* fc1w_f = (float*)take(S_F1W*4);
    float* fc1b_f = (float*)take(S_F1B*4);
    float* fc2w_f = (float*)take(S_F2W*4);
    float* fc2b_f = (float*)take(S_F2B*4);
    u16*   E_iou  = (u16*)  take((size_t)VPAD*768*2);      // 15.4 MB
    u16*   E_f    = (u16*)  take((size_t)VPAD*DD*2);
    u16*   H0     = (u16*)  take((size_t)VPAD*DD*2);
    u16*   C0     = (u16*)  take((size_t)VPAD*DD*2);
    u16*   HU0    = (u16*)  take((size_t)VPAD*DD*2);
    u16*   HB     = (u16*)  take((size_t)12288*DD*2);      // hsum, odd-lvl writes (lvl1 out)
    u16*   FB     = (u16*)  take((size_t)12288*DD*2);
    u16*   HA     = (u16*)  take((size_t)6144*DD*2);       // hsum, even-lvl writes
    u16*   FA     = (u16*)  take((size_t)6144*DD*2);
    u16*   hroot  = (u16*)  take((size_t)NRUNS*NTREE*DD*2);
    // total ~55 MB (< proven 119 MB)

    k_detect<<<1, 256, 0, stream>>>((const u16*)emb, flag);
    k_cvtall<<<2048, 256, 0, stream>>>(emb, Wiou, Uiou, Wf, Uf,
                                       biou, bfv, fc1w, fc1b, fc2w, fc2b,
                                       embb, wioub, uioub, wfb, ufb,
                                       biou_f, bf_f, fc1w_f, fc1b_f, fc2w_f, fc2b_f, flag);
    k_vocab2<<<VPAD/32, 512, 0, stream>>>(embb, wioub, wfb, ufb, biou_f,
                                          E_iou, E_f, H0, C0, HU0);
    // level 1 fused with edge assembly (24576 rows, 768 blocks) -> writes HB/FB
    k_lvl1<<<768, 512, 0, stream>>>(f0, f1, f2, E_iou, E_f, H0, C0, HU0,
                                    uioub, ufb, biou_f, bf_f, HB, FB);

    for (int lvl = 2; lvl <= 7; lvl++){
        int cLog = 7 - lvl;
        int rows = NRUNS*NTREE*(128 >> lvl);
        int blocks = rows / 32;
        int pe = lvl & 1;
        u16* hs_o = pe ? HB : HA;
        u16* fc_o = pe ? FB : FA;
        const u16* hs_i = pe ? HA : HB;
        const u16* fc_i = pe ? FA : FB;
        k_lvl<<<blocks, 512, 0, stream>>>(lvl, cLog, f0, f1, f2,
                                          E_iou, E_f, uioub, ufb,
                                          biou_f, bf_f,
                                          hs_i, fc_i, hs_o, fc_o, hroot);
    }
    k_final<<<NTREE, 256, 0, stream>>>(hroot, fc1w_f, fc1b_f, fc2w_f, fc2b_f, d_out, flag);
}